// Round 1
// baseline (237.013 us; speedup 1.0000x reference)
//
#include <hip/hip_runtime.h>
#include <hip/hip_bf16.h>

// SO3TensorProductLayer: out = relu(128*(x^T W1_c x) + b1) @ W2 + b2
// Factorization: h[b,c] = 128 * sum_i x[b,i] * (sum_j W1T[c][i*128+j] * x[b,j])
// Inner contraction via mfma_f32_16x16x32_bf16 with A=W1T (global->VGPR direct,
// no LDS staging, no K-loop barrier), B=x held in registers; per-i scalar fold.

typedef __attribute__((ext_vector_type(8))) short short8;   // 8 bf16 (4 VGPRs)
typedef __attribute__((ext_vector_type(4))) float floatx4;  // 4 fp32 acc

__device__ __forceinline__ unsigned short f2bf(float f) {
    union { float f; unsigned int u; } v; v.f = f;
    unsigned int r = v.u + 0x7fffu + ((v.u >> 16) & 1u);   // RNE
    return (unsigned short)(r >> 16);
}
__device__ __forceinline__ float bf2f(unsigned short b) {
    union { unsigned int u; float f; } v; v.u = ((unsigned int)b) << 16;
    return v.f;
}

// in: [R][C] fp32 -> out: [C][R] bf16 (transpose + cast). grid (R/64, C/64), 256 thr.
__global__ __launch_bounds__(256) void transpose_cast_kernel(
    const float* __restrict__ in, unsigned short* __restrict__ out, int R, int C) {
    __shared__ float tile[64][65];
    const int r0 = blockIdx.x * 64, c0 = blockIdx.y * 64;
    const int tr = threadIdx.x >> 4;            // 0..15
    const int tc4 = (threadIdx.x & 15) * 4;     // 0..60 step 4
#pragma unroll
    for (int p = 0; p < 4; ++p) {
        int r = p * 16 + tr;
        float4 v = *(const float4*)(in + (long)(r0 + r) * C + c0 + tc4);
        tile[r][tc4 + 0] = v.x; tile[r][tc4 + 1] = v.y;
        tile[r][tc4 + 2] = v.z; tile[r][tc4 + 3] = v.w;
    }
    __syncthreads();
#pragma unroll
    for (int p = 0; p < 4; ++p) {
        int c = p * 16 + tr;                    // output row (c-dim)
        union { unsigned short s[4]; uint2 u; } pk;
#pragma unroll
        for (int e = 0; e < 4; ++e) pk.s[e] = f2bf(tile[tc4 + e][c]);
        *(uint2*)(out + (long)(c0 + c) * R + r0 + tc4) = pk.u;
    }
}

// Big GEMM: partials[bz][c][b] = sum_{i in chunk} x[b,i] * sum_j W1T[c][i*128+j]*x[b,j]
// block: 512 thr = 8 waves (2 c-waves x 4 b-waves), tile 128c x 256b, split-K=4 over i.
__global__ __launch_bounds__(512, 2) void gemm1_kernel(
    const float* __restrict__ x,               // [4096][128] fp32
    const unsigned short* __restrict__ W1T,    // [512][16384] bf16
    float* __restrict__ partials) {            // [4][512][4096] fp32
    __shared__ unsigned short xT[32][264];     // [i_local][b_local], padded

    const int tid = threadIdx.x;
    const int b0 = blockIdx.x * 256;
    const int c0 = blockIdx.y * 128;
    const int i0 = blockIdx.z * 32;

    // stage xT (fold multipliers): xT[i][b_local] = bf16(x[b0+b][i0+i])
    for (int idx = tid; idx < 32 * 256; idx += 512) {
        int iL = idx & 31;
        int bL = idx >> 5;
        xT[iL][bL] = f2bf(x[(long)(b0 + bL) * 128 + i0 + iL]);
    }
    __syncthreads();

    const int wid = tid >> 6;
    const int wm = wid >> 2;                   // 0..1  (c)
    const int wn = wid & 3;                    // 0..3  (b)
    const int lane = tid & 63;
    const int n16 = lane & 15;
    const int quad = lane >> 4;
    const int cBase = c0 + wm * 64;
    const int bBase = b0 + wn * 64;

    floatx4 acc[4][4];                         // [tm(c)][tn(b)]
#pragma unroll
    for (int tm = 0; tm < 4; ++tm)
#pragma unroll
        for (int tn = 0; tn < 4; ++tn) acc[tm][tn] = (floatx4){0.f, 0.f, 0.f, 0.f};

    const floatx4 zero4 = (floatx4){0.f, 0.f, 0.f, 0.f};

    for (int jh = 0; jh < 2; ++jh) {
        const int jBase = jh * 64;
        // x B-fragments for this j-half, held in registers: B[k=j][n=b]
        short8 Xf[2][4];                       // [ks][tn]
#pragma unroll
        for (int ks = 0; ks < 2; ++ks)
#pragma unroll
            for (int tn = 0; tn < 4; ++tn) {
                const float* xp = x + (long)(bBase + tn * 16 + n16) * 128
                                    + jBase + ks * 32 + quad * 8;
                float4 v0 = *(const float4*)xp;
                float4 v1 = *(const float4*)(xp + 4);
                short8 f;
                f[0] = (short)f2bf(v0.x); f[1] = (short)f2bf(v0.y);
                f[2] = (short)f2bf(v0.z); f[3] = (short)f2bf(v0.w);
                f[4] = (short)f2bf(v1.x); f[5] = (short)f2bf(v1.y);
                f[6] = (short)f2bf(v1.z); f[7] = (short)f2bf(v1.w);
                Xf[ks][tn] = f;
            }
        // per-tm A row pointers (W1T rows = c, k-contiguous)
        const unsigned short* aRow[4];
#pragma unroll
        for (int tm = 0; tm < 4; ++tm)
            aRow[tm] = W1T + (long)(cBase + tm * 16 + n16) * 16384
                           + (long)i0 * 128 + jBase + quad * 8;

        short8 Acur[2][4], Anext[2][4];
#pragma unroll
        for (int ks = 0; ks < 2; ++ks)
#pragma unroll
            for (int tm = 0; tm < 4; ++tm)
                Acur[ks][tm] = *(const short8*)(aRow[tm] + ks * 32);

#pragma unroll 2
        for (int i = 0; i < 32; ++i) {
            if (i < 31) {                      // prefetch next i (wave-uniform branch)
#pragma unroll
                for (int ks = 0; ks < 2; ++ks)
#pragma unroll
                    for (int tm = 0; tm < 4; ++tm)
                        Anext[ks][tm] = *(const short8*)(aRow[tm] + (i + 1) * 128 + ks * 32);
            }
            float xi[4];
#pragma unroll
            for (int tn = 0; tn < 4; ++tn)
                xi[tn] = bf2f(xT[i][wn * 64 + tn * 16 + n16]);
#pragma unroll
            for (int tm = 0; tm < 4; ++tm)
#pragma unroll
                for (int tn = 0; tn < 4; ++tn) {
                    floatx4 t = __builtin_amdgcn_mfma_f32_16x16x32_bf16(
                        Acur[0][tm], Xf[0][tn], zero4, 0, 0, 0);
                    t = __builtin_amdgcn_mfma_f32_16x16x32_bf16(
                        Acur[1][tm], Xf[1][tn], t, 0, 0, 0);
                    acc[tm][tn] += xi[tn] * t;
                }
#pragma unroll
            for (int ks = 0; ks < 2; ++ks)
#pragma unroll
                for (int tm = 0; tm < 4; ++tm) Acur[ks][tm] = Anext[ks][tm];
        }
    }

    // store partial block (layout [c][b], coalesced over lane&15)
    float* pbase = partials + (long)blockIdx.z * (512L * 4096);
#pragma unroll
    for (int tm = 0; tm < 4; ++tm)
#pragma unroll
        for (int tn = 0; tn < 4; ++tn)
#pragma unroll
            for (int r = 0; r < 4; ++r) {
                int c = cBase + tm * 16 + quad * 4 + r;
                int b = bBase + tn * 16 + n16;
                pbase[(long)c * 4096 + b] = acc[tm][tn][r];
            }
}

// combine: h[b][c] = bf16(relu(128*(P0+P1+P2+P3)[c][b] + b1[c]))  (transpose c,b -> b,c)
__global__ __launch_bounds__(256) void combine_kernel(
    const float* __restrict__ partials,        // [4][512][4096]
    const float* __restrict__ b1,              // [512]
    unsigned short* __restrict__ h) {          // [4096][512] bf16
    __shared__ float tile[64][65];             // [c][b]
    const int b0 = blockIdx.x * 64;
    const int c0 = blockIdx.y * 64;
    const int tr = threadIdx.x >> 6;           // 0..3
    const int tb = threadIdx.x & 63;           // 0..63
#pragma unroll
    for (int p = 0; p < 16; ++p) {
        int c = p * 4 + tr;
        long off = (long)(c0 + c) * 4096 + b0 + tb;
        float s = partials[off] + partials[off + 512L * 4096]
                + partials[off + 2 * 512L * 4096] + partials[off + 3 * 512L * 4096];
        tile[c][tb] = s;
    }
    __syncthreads();
    const int tbr = threadIdx.x >> 4;          // 0..15 (b row)
    const int tc4 = (threadIdx.x & 15) * 4;    // c col group
#pragma unroll
    for (int p = 0; p < 4; ++p) {
        int b = p * 16 + tbr;
        union { unsigned short s[4]; uint2 u; } pk;
#pragma unroll
        for (int e = 0; e < 4; ++e) {
            float v = 128.0f * tile[tc4 + e][b] + b1[c0 + tc4 + e];
            pk.s[e] = f2bf(fmaxf(v, 0.0f));
        }
        *(uint2*)(h + (long)(b0 + b) * 512 + c0 + tc4) = pk.u;
    }
}

// out[b][o] = sum_c h[b][c]*W2T[o][c] + b2[o].  block 256 thr = 4 waves, tile 128b x 64o.
__global__ __launch_bounds__(256) void gemm2_kernel(
    const unsigned short* __restrict__ h,      // [4096][512] bf16
    const unsigned short* __restrict__ W2T,    // [256][512] bf16
    const float* __restrict__ b2,              // [256]
    float* __restrict__ out) {                 // [4096][256] fp32
    const int tid = threadIdx.x;
    const int wid = tid >> 6;
    const int wm = wid >> 1;                   // 0..1 (b)
    const int wn = wid & 1;                    // 0..1 (o)
    const int lane = tid & 63;
    const int n16 = lane & 15;
    const int quad = lane >> 4;
    const int b0 = blockIdx.x * 128 + wm * 64;
    const int o0 = blockIdx.y * 64 + wn * 32;

    floatx4 acc[4][2];
#pragma unroll
    for (int tm = 0; tm < 4; ++tm)
#pragma unroll
        for (int tn = 0; tn < 2; ++tn) acc[tm][tn] = (floatx4){0.f, 0.f, 0.f, 0.f};

#pragma unroll 2
    for (int ks = 0; ks < 16; ++ks) {
        short8 Af[4], Bf[2];
#pragma unroll
        for (int tm = 0; tm < 4; ++tm)
            Af[tm] = *(const short8*)(h + (long)(b0 + tm * 16 + n16) * 512 + ks * 32 + quad * 8);
#pragma unroll
        for (int tn = 0; tn < 2; ++tn)
            Bf[tn] = *(const short8*)(W2T + (long)(o0 + tn * 16 + n16) * 512 + ks * 32 + quad * 8);
#pragma unroll
        for (int tm = 0; tm < 4; ++tm)
#pragma unroll
            for (int tn = 0; tn < 2; ++tn)
                acc[tm][tn] = __builtin_amdgcn_mfma_f32_16x16x32_bf16(
                    Af[tm], Bf[tn], acc[tm][tn], 0, 0, 0);
    }
#pragma unroll
    for (int tn = 0; tn < 2; ++tn) {
        float bias = b2[o0 + tn * 16 + n16];
#pragma unroll
        for (int tm = 0; tm < 4; ++tm)
#pragma unroll
            for (int r = 0; r < 4; ++r) {
                int b = b0 + tm * 16 + quad * 4 + r;
                int o = o0 + tn * 16 + n16;
                out[(long)b * 256 + o] = acc[tm][tn][r] + bias;
            }
    }
}

extern "C" void kernel_launch(void* const* d_in, const int* in_sizes, int n_in,
                              void* d_out, int out_size, void* d_ws, size_t ws_size,
                              hipStream_t stream) {
    const float* x  = (const float*)d_in[0];   // [4096,128]
    const float* W1 = (const float*)d_in[1];   // [16384,512]
    const float* b1 = (const float*)d_in[2];   // [512]
    const float* W2 = (const float*)d_in[3];   // [512,256]
    const float* b2 = (const float*)d_in[4];   // [256]
    float* out = (float*)d_out;                // [4096,256]

    char* ws = (char*)d_ws;
    unsigned short* W1T     = (unsigned short*)(ws);                        // 16.78 MB
    unsigned short* W2T     = (unsigned short*)(ws + 16777216);             // 0.26 MB
    float*          parts   = (float*)(ws + 16777216 + 262144);             // 33.55 MB
    unsigned short* h       = (unsigned short*)(ws + 16777216 + 262144 + 33554432); // 4.19 MB

    transpose_cast_kernel<<<dim3(16384 / 64, 512 / 64), 256, 0, stream>>>(W1, W1T, 16384, 512);
    transpose_cast_kernel<<<dim3(512 / 64, 256 / 64), 256, 0, stream>>>(W2, W2T, 512, 256);
    gemm1_kernel<<<dim3(16, 4, 4), 512, 0, stream>>>(x, W1T, parts);
    combine_kernel<<<dim3(64, 8), 256, 0, stream>>>(parts, b1, h);
    gemm2_kernel<<<dim3(32, 4), 256, 0, stream>>>(h, W2T, b2, out);
}

// Round 2
// 177.950 us; speedup vs baseline: 1.3319x; 1.3319x over previous
//
#include <hip/hip_runtime.h>
#include <hip/hip_bf16.h>

// SO3TensorProductLayer: out = relu(128*(x (x) x) @ W1 + b1) @ W2 + b2
// h[c][b] = 128 * sum_i x[b,i] * (sum_j W1T[c][i*128+j] * x[b,j])
// gemm1: A = W1 packed in MFMA-fragment order (1KB contiguous wave loads,
// global->VGPR, 2-stage rotating buffer, no K-loop barrier); B = x in regs;
// per-i scalar fold by x[b,i]. Tail kernel fuses partial-sum+bias+relu+gemm2.

typedef __attribute__((ext_vector_type(8))) short short8;   // 8 bf16
typedef __attribute__((ext_vector_type(4))) float floatx4;  // 4 fp32

__device__ __forceinline__ unsigned short f2bf(float f) {
    union { float f; unsigned int u; } v; v.f = f;
    unsigned int r = v.u + 0x7fffu + ((v.u >> 16) & 1u);   // RNE
    return (unsigned short)(r >> 16);
}
__device__ __forceinline__ float bf2f(unsigned short b) {
    union { unsigned int u; float f; } v; v.u = ((unsigned int)b) << 16;
    return v.f;
}

// ---------------------------------------------------------------------------
// Pack W1 [16384 K][512 C] fp32 -> W1Tp chunks of 1KB: chunk(c16,kc) holds
// A-fragment for c rows c16*16..+15, K cols kc*32..+31, laid out so a wave
// load at (chunkBase + lane*16B) yields lane(m=lane&15,quad=lane>>4) the
// 8 bf16 of W1[K=kc*32+quad*8+j][c=c16*16+m].
__global__ __launch_bounds__(256) void pack_w1_kernel(
    const float* __restrict__ W1, unsigned short* __restrict__ W1Tp) {
    __shared__ float tile[64][65];
    const int k0 = blockIdx.x * 64;
    const int c0 = blockIdx.y * 64;
    const int tr = threadIdx.x >> 4;
    const int tc4 = (threadIdx.x & 15) * 4;
#pragma unroll
    for (int p = 0; p < 4; ++p) {
        int k = p * 16 + tr;
        float4 v = *(const float4*)(W1 + (long)(k0 + k) * 512 + c0 + tc4);
        tile[k][tc4 + 0] = v.x; tile[k][tc4 + 1] = v.y;
        tile[k][tc4 + 2] = v.z; tile[k][tc4 + 3] = v.w;
    }
    __syncthreads();
    const int lane = threadIdx.x & 63;
    const int w = threadIdx.x >> 6;
    const int m = lane & 15, quad = lane >> 4;
#pragma unroll
    for (int pass = 0; pass < 2; ++pass) {
        int chunk = w * 2 + pass;              // 0..7
        int kcL = chunk & 1, c16L = chunk >> 1;
        union { unsigned short s[8]; uint4 u; } o;
#pragma unroll
        for (int j = 0; j < 8; ++j)
            o.s[j] = f2bf(tile[kcL * 32 + quad * 8 + j][c16L * 16 + m]);
        long c16g = (c0 >> 4) + c16L;
        long kcg  = (k0 >> 5) + kcL;
        *(uint4*)(W1Tp + (c16g * 512 + kcg) * 512 + lane * 8) = o.u;
    }
}

// in: [R][C] fp32 -> out: [C][R] bf16 (for W2 -> W2T).
__global__ __launch_bounds__(256) void transpose_cast_kernel(
    const float* __restrict__ in, unsigned short* __restrict__ out, int R, int C) {
    __shared__ float tile[64][65];
    const int r0 = blockIdx.x * 64, c0 = blockIdx.y * 64;
    const int tr = threadIdx.x >> 4;
    const int tc4 = (threadIdx.x & 15) * 4;
#pragma unroll
    for (int p = 0; p < 4; ++p) {
        int r = p * 16 + tr;
        float4 v = *(const float4*)(in + (long)(r0 + r) * C + c0 + tc4);
        tile[r][tc4 + 0] = v.x; tile[r][tc4 + 1] = v.y;
        tile[r][tc4 + 2] = v.z; tile[r][tc4 + 3] = v.w;
    }
    __syncthreads();
#pragma unroll
    for (int p = 0; p < 4; ++p) {
        int c = p * 16 + tr;
        union { unsigned short s[4]; uint2 u; } pk;
#pragma unroll
        for (int e = 0; e < 4; ++e) pk.s[e] = f2bf(tile[tc4 + e][c]);
        *(uint2*)(out + (long)(c0 + c) * R + r0 + tc4) = pk.u;
    }
}

// ---------------------------------------------------------------------------
// gemm1: partials[z][c][b] over i-chunk z. 256 thr = 4 waves (2c x 2b),
// tile 64c x 128b, per-wave 2tm x 4tn. grid (32 b, 8 c, 4 z) = 1024 blocks
// -> 4 blocks/CU, 4 waves/SIMD at <=128 VGPR.
__global__ __launch_bounds__(256, 4) void gemm1_kernel(
    const float* __restrict__ x,               // [4096][128]
    const unsigned short* __restrict__ W1Tp,
    float* __restrict__ partials) {            // [4][512][4096]
    __shared__ unsigned short xT[32][136];
    const int tid = threadIdx.x;
    const int b0 = blockIdx.x * 128;
    const int c0 = blockIdx.y * 64;
    const int i0 = blockIdx.z * 32;

    for (int idx = tid; idx < 32 * 128; idx += 256) {
        int iL = idx & 31, bL = idx >> 5;
        xT[iL][bL] = f2bf(x[(long)(b0 + bL) * 128 + i0 + iL]);
    }
    __syncthreads();

    const int wid = tid >> 6;
    const int wm = wid >> 1, wn = wid & 1;
    const int lane = tid & 63;
    const int n16 = lane & 15, quad = lane >> 4;
    const int bBase = b0 + wn * 64;
    const int c16base = (c0 >> 4) + wm * 2;

    floatx4 acc[2][4];
#pragma unroll
    for (int tm = 0; tm < 2; ++tm)
#pragma unroll
        for (int tn = 0; tn < 4; ++tn) acc[tm][tn] = (floatx4){0.f, 0.f, 0.f, 0.f};
    const floatx4 zero4 = (floatx4){0.f, 0.f, 0.f, 0.f};

#pragma unroll
    for (int jh = 0; jh < 2; ++jh) {
        // x B-fragments, register-resident for this j-half
        short8 Xf[2][4];
#pragma unroll
        for (int ks = 0; ks < 2; ++ks)
#pragma unroll
            for (int tn = 0; tn < 4; ++tn) {
                const float* xp = x + (long)(bBase + tn * 16 + n16) * 128
                                    + jh * 64 + ks * 32 + quad * 8;
                float4 v0 = *(const float4*)xp;
                float4 v1 = *(const float4*)(xp + 4);
                short8 f;
                f[0] = (short)f2bf(v0.x); f[1] = (short)f2bf(v0.y);
                f[2] = (short)f2bf(v0.z); f[3] = (short)f2bf(v0.w);
                f[4] = (short)f2bf(v1.x); f[5] = (short)f2bf(v1.y);
                f[6] = (short)f2bf(v1.z); f[7] = (short)f2bf(v1.w);
                Xf[ks][tn] = f;
            }
        // A chunk base pointers; i-advance = 4 chunks = 2048 u16 = 4KB... (x2)
        const unsigned short* aBase[2][2];
#pragma unroll
        for (int tm = 0; tm < 2; ++tm)
#pragma unroll
            for (int ks = 0; ks < 2; ++ks)
                aBase[tm][ks] = W1Tp
                    + ((long)(c16base + tm) * 512 + (long)i0 * 4 + jh * 2 + ks) * 512
                    + lane * 8;

        short8 Abuf[2][2][2];                  // [stage][tm][ks]
#pragma unroll
        for (int tm = 0; tm < 2; ++tm)
#pragma unroll
            for (int ks = 0; ks < 2; ++ks) {
                Abuf[0][tm][ks] = *(const short8*)(aBase[tm][ks]);
                Abuf[1][tm][ks] = *(const short8*)(aBase[tm][ks] + 2048);
            }
#pragma unroll 4
        for (int i = 0; i < 32; ++i) {
            const int st = i & 1;
            float xi[4];
#pragma unroll
            for (int tn = 0; tn < 4; ++tn)
                xi[tn] = bf2f(xT[i][wn * 64 + tn * 16 + n16]);
#pragma unroll
            for (int tm = 0; tm < 2; ++tm)
#pragma unroll
                for (int tn = 0; tn < 4; ++tn) {
                    floatx4 t = __builtin_amdgcn_mfma_f32_16x16x32_bf16(
                        Abuf[st][tm][0], Xf[0][tn], zero4, 0, 0, 0);
                    t = __builtin_amdgcn_mfma_f32_16x16x32_bf16(
                        Abuf[st][tm][1], Xf[1][tn], t, 0, 0, 0);
                    acc[tm][tn] += xi[tn] * t;
                }
            const int pi = (i + 2) & 31;       // wrap: tail reload is harmless
#pragma unroll
            for (int tm = 0; tm < 2; ++tm)
#pragma unroll
                for (int ks = 0; ks < 2; ++ks)
                    Abuf[st][tm][ks] =
                        *(const short8*)(aBase[tm][ks] + (long)pi * 2048);
        }
    }

    float* pbase = partials + (long)blockIdx.z * (512L * 4096);
#pragma unroll
    for (int tm = 0; tm < 2; ++tm)
#pragma unroll
        for (int tn = 0; tn < 4; ++tn)
#pragma unroll
            for (int r = 0; r < 4; ++r) {
                int c = (c16base + tm) * 16 + quad * 4 + r;
                int b = bBase + tn * 16 + n16;
                pbase[(long)c * 4096 + b] = acc[tm][tn][r];
            }
}

// ---------------------------------------------------------------------------
// tail: h[b][c] = relu(128*sum_z P[z][c][b] + b1[c]) (bf16, LDS), then
// out[b][o] = h @ W2T + b2. 256 thr = 4 waves; b-tile 32; each wave owns 64 o.
__global__ __launch_bounds__(256) void tail_kernel(
    const float* __restrict__ partials,        // [4][512][4096]
    const float* __restrict__ b1,              // [512]
    const unsigned short* __restrict__ W2T,    // [256][512] bf16
    const float* __restrict__ b2,              // [256]
    float* __restrict__ out) {                 // [4096][256]
    __shared__ unsigned short hL[32][516];     // stride 516 u16: 8B-aligned rows, conflict-light
    __shared__ float b1s[512];
    const int tid = threadIdx.x;
    const int b0 = blockIdx.x * 32;
    b1s[tid] = b1[tid];
    b1s[tid + 256] = b1[tid + 256];
    __syncthreads();

    const int bL = tid & 31;
    const int cr = tid >> 5;                   // 0..7
    const long P = 512L * 4096;
#pragma unroll 4
    for (int cp = cr; cp < 256; cp += 8) {
        int c = cp * 2;
        long off0 = (long)c * 4096 + b0 + bL;
        float s0 = partials[off0] + partials[off0 + P]
                 + partials[off0 + 2 * P] + partials[off0 + 3 * P];
        long off1 = off0 + 4096;
        float s1 = partials[off1] + partials[off1 + P]
                 + partials[off1 + 2 * P] + partials[off1 + 3 * P];
        float v0 = fmaxf(fmaf(128.f, s0, b1s[c]), 0.f);
        float v1 = fmaxf(fmaf(128.f, s1, b1s[c + 1]), 0.f);
        unsigned int pk = (unsigned int)f2bf(v0) | ((unsigned int)f2bf(v1) << 16);
        *(unsigned int*)&hL[bL][c] = pk;
    }
    __syncthreads();

    const int w = tid >> 6, lane = tid & 63;
    const int n16 = lane & 15, quad = lane >> 4;
    const int o0 = w * 64;
    floatx4 acc[2][4];
#pragma unroll
    for (int tm = 0; tm < 2; ++tm)
#pragma unroll
        for (int tn = 0; tn < 4; ++tn) acc[tm][tn] = (floatx4){0.f, 0.f, 0.f, 0.f};

#pragma unroll 4
    for (int ks = 0; ks < 16; ++ks) {
        short8 Af[2], Bf[4];
#pragma unroll
        for (int tm = 0; tm < 2; ++tm) {
            const unsigned short* p = &hL[tm * 16 + n16][ks * 32 + quad * 8];
            union { uint2 u[2]; short8 s; } cvt;
            cvt.u[0] = *(const uint2*)p;
            cvt.u[1] = *(const uint2*)(p + 4);
            Af[tm] = cvt.s;
        }
#pragma unroll
        for (int tn = 0; tn < 4; ++tn)
            Bf[tn] = *(const short8*)(W2T + (long)(o0 + tn * 16 + n16) * 512
                                      + ks * 32 + quad * 8);
#pragma unroll
        for (int tm = 0; tm < 2; ++tm)
#pragma unroll
            for (int tn = 0; tn < 4; ++tn)
                acc[tm][tn] = __builtin_amdgcn_mfma_f32_16x16x32_bf16(
                    Af[tm], Bf[tn], acc[tm][tn], 0, 0, 0);
    }
#pragma unroll
    for (int tn = 0; tn < 4; ++tn) {
        float bias = b2[o0 + tn * 16 + n16];
#pragma unroll
        for (int tm = 0; tm < 2; ++tm)
#pragma unroll
            for (int r = 0; r < 4; ++r)
                out[(long)(b0 + tm * 16 + quad * 4 + r) * 256
                    + o0 + tn * 16 + n16] = acc[tm][tn][r] + bias;
    }
}

extern "C" void kernel_launch(void* const* d_in, const int* in_sizes, int n_in,
                              void* d_out, int out_size, void* d_ws, size_t ws_size,
                              hipStream_t stream) {
    const float* x  = (const float*)d_in[0];   // [4096,128]
    const float* W1 = (const float*)d_in[1];   // [16384,512]
    const float* b1 = (const float*)d_in[2];   // [512]
    const float* W2 = (const float*)d_in[3];   // [512,256]
    const float* b2 = (const float*)d_in[4];   // [256]
    float* out = (float*)d_out;                // [4096,256]

    char* ws = (char*)d_ws;
    unsigned short* W1Tp = (unsigned short*)(ws);                 // 16.78 MB
    unsigned short* W2T  = (unsigned short*)(ws + 16777216);      // 0.26 MB
    float*          parts = (float*)(ws + 16777216 + 262144);     // 33.55 MB

    pack_w1_kernel<<<dim3(256, 8), 256, 0, stream>>>(W1, W1Tp);
    transpose_cast_kernel<<<dim3(8, 4), 256, 0, stream>>>(W2, W2T, 512, 256);
    gemm1_kernel<<<dim3(32, 8, 4), 256, 0, stream>>>(x, W1Tp, parts);
    tail_kernel<<<dim3(128), 256, 0, stream>>>(parts, b1, W2T, b2, out);
}